// Round 1
// baseline (259.727 us; speedup 1.0000x reference)
//
#include <hip/hip_runtime.h>
#include <math.h>

#define BB 8
#define XD 32
#define DD 128
#define KK 256
#define HH 2
#define XYZ 32768
#define EPSV 1e-5f

// ws layout (float offsets)
#define WS_SS   0                     // 4 floats: sum-of-squares of Vx,Vy,Vz,Vh
#define WS_X    16                    // [B*32, 256] = 65536
#define WS_Y    (WS_X + 65536)
#define WS_Z    (WS_Y + 65536)
#define WS_RAW  (WS_Z + 65536)        // [B,H,XYZ] = 524288
#define WS_PART (WS_RAW + 524288)     // [B,32,256] = 65536
// total = 786448 floats ~ 3.0 MB

// ---------------------------------------------------------------- norms
__global__ void tan_norm_kernel(const float* Vx, const float* Vy,
                                const float* Vz, const float* Vh, float* ws) {
    __shared__ float red[256];
    int w = blockIdx.x;
    const float* p = (w == 0) ? Vx : (w == 1) ? Vy : (w == 2) ? Vz : Vh;
    int n = (w == 3) ? (HH * KK) : (KK * DD);
    float s = 0.f;
    for (int i = threadIdx.x; i < n; i += 256) { float v = p[i]; s += v * v; }
    red[threadIdx.x] = s;
    __syncthreads();
    for (int st = 128; st > 0; st >>= 1) {
        if (threadIdx.x < st) red[threadIdx.x] += red[threadIdx.x + st];
        __syncthreads();
    }
    if (threadIdx.x == 0) ws[WS_SS + w] = red[0];
}

// ---------------------------------------------------------------- projections
// grid 768: which = bid>>8 (0:x 1:y 2:z), row = bid&255 (b*32+i)
__global__ void tan_proj_kernel(const float* x, const float* y, const float* z,
                                const float* Vx, const float* Vy, const float* Vz,
                                const float* gx, const float* gy, const float* gz,
                                const float* bx, const float* by, const float* bz,
                                float* ws) {
    __shared__ float lin[DD];
    int bid = blockIdx.x;
    int which = bid >> 8;
    int row = bid & 255;
    const float *in, *V, *g, *bias;
    float* outp;
    if (which == 0)      { in = x; V = Vx; g = gx; bias = bx; outp = ws + WS_X; }
    else if (which == 1) { in = y; V = Vy; g = gy; bias = by; outp = ws + WS_Y; }
    else                 { in = z; V = Vz; g = gz; bias = bz; outp = ws + WS_Z; }
    float scale = g[0] * rsqrtf(ws[WS_SS + which]);
    int t = threadIdx.x;
    if (t < DD) lin[t] = in[row * DD + t];
    __syncthreads();
    const float4* v4 = (const float4*)(V + t * DD);
    const float4* l4 = (const float4*)lin;
    float acc = 0.f;
#pragma unroll 8
    for (int d4 = 0; d4 < DD / 4; ++d4) {
        float4 a = v4[d4];
        float4 b = l4[d4];
        acc += a.x * b.x + a.y * b.y + a.z * b.z + a.w * b.w;
    }
    float v = acc * scale + bias[t];
    outp[row * KK + t] = fmaxf(v, 0.f);
}

// ---------------------------------------------------------------- raw scores
// grid 128: b = bid>>4, grp = bid&15 (64 xy rows per block), 256 threads
__global__ void tan_score_kernel(const float* Vh, const float* gh,
                                 const float* bh, float* ws) {
    __shared__ float zw[128 * 64];  // zw[kl*64 + th], 32 KB
    __shared__ float T[4 * 128];    // T[sub*128 + kl], 2 KB
    int t = threadIdx.x;
    int bb = blockIdx.x >> 4;
    int grp = blockIdx.x & 15;
    int th = t & 63;
    int zi = t & 31;
    int hi = (t >> 5) & 1;
    int sub = t >> 6;
    float sh = gh[0] * rsqrtf(ws[WS_SS + 3]);
    const float* _zb = ws + WS_Z + bb * 8192;
    const float* _xb = ws + WS_X + bb * 8192;
    const float* _yb = ws + WS_Y + bb * 8192;
    float* raw = ws + WS_RAW;

    float acc[16];
#pragma unroll
    for (int g = 0; g < 16; ++g) acc[g] = 0.f;

    for (int c = 0; c < 2; ++c) {
        // stage zw chunk: zw[kl][th] = _z[b, z(th), kg] * sh*Vh[h(th), kg]
        for (int i = 0; i < 32; ++i) {
            int idx = i * 256 + t;
            int kl = idx >> 6;
            int t2 = idx & 63;
            int kg = c * 128 + kl;
            zw[idx] = _zb[(t2 & 31) * KK + kg] * (sh * Vh[((t2 >> 5) & 1) * KK + kg]);
        }
        __syncthreads();
        for (int g = 0; g < 16; ++g) {
            int xy = grp * 64 + g * 4 + sub;
            int xx = xy >> 5, yy = xy & 31;
            int kk = (t & 63) * 2;
            int kg = c * 128 + kk;
            float2 xv = *(const float2*)(_xb + xx * KK + kg);
            float2 yv = *(const float2*)(_yb + yy * KK + kg);
            T[sub * 128 + kk] = xv.x * yv.x;
            T[sub * 128 + kk + 1] = xv.y * yv.y;
            __syncthreads();
            float a = 0.f;
#pragma unroll 8
            for (int kl = 0; kl < 128; ++kl)
                a += T[sub * 128 + kl] * zw[kl * 64 + th];
            acc[g] += a;
            __syncthreads();
        }
    }
    float bias = bh[hi];
    for (int g = 0; g < 16; ++g) {
        int xy = grp * 64 + g * 4 + sub;
        raw[(bb * 2 + hi) * XYZ + xy * 32 + zi] = acc[g] + bias;
    }
}

// ---------------------------------------------------------------- softmax
// grid 16 (= b*2+h), 1024 threads; writes att to d_out + 2048
__global__ void tan_softmax_kernel(float* ws, float* out) {
    __shared__ float red[1024];
    int bh = blockIdx.x;
    const float* raw = ws + WS_RAW + bh * XYZ;
    float* att = out + BB * KK + bh * XYZ;
    int t = threadIdx.x;
    float m = -1e30f;
    for (int i = t; i < XYZ; i += 1024) m = fmaxf(m, raw[i]);
    red[t] = m;
    __syncthreads();
    for (int s = 512; s > 0; s >>= 1) {
        if (t < s) red[t] = fmaxf(red[t], red[t + s]);
        __syncthreads();
    }
    m = red[0];
    __syncthreads();
    float sum = 0.f;
    for (int i = t; i < XYZ; i += 1024) sum += expf(raw[i] - m);
    red[t] = sum;
    __syncthreads();
    for (int s = 512; s > 0; s >>= 1) {
        if (t < s) red[t] += red[t + s];
        __syncthreads();
    }
    float inv = 1.f / red[0];
    for (int i = t; i < XYZ; i += 1024) att[i] = expf(raw[i] - m) * inv;
}

// ---------------------------------------------------------------- logits partials
// grid 256: b = bid>>5, x = bid&31; 256 threads (thread = k)
__global__ void tan_logits_kernel(float* ws, const float* out) {
    __shared__ float lz[XD * KK];  // 32 KB: lz[z*256 + k]
    __shared__ float as[1024];     // att_sum[b,x,y,z] for this (b,x)
    int b = blockIdx.x >> 5;
    int x = blockIdx.x & 31;
    int t = threadIdx.x;
    const float* _zb = ws + WS_Z + b * 8192;
    for (int i = t; i < 8192; i += 256) lz[i] = _zb[i];
    const float* a0 = out + BB * KK + (b * 2) * XYZ + x * 1024;
    const float* a1 = a0 + XYZ;
    for (int i = t; i < 1024; i += 256) as[i] = a0[i] + a1[i];
    __syncthreads();
    const float* _yb = ws + WS_Y + b * 8192;
    float acc = 0.f;
    for (int y = 0; y < 32; ++y) {
        float s = 0.f;
        const float* ar = as + y * 32;
#pragma unroll
        for (int zi = 0; zi < 32; ++zi) s += ar[zi] * lz[zi * 256 + t];
        acc += _yb[y * 256 + t] * s;
    }
    float xv = ws[WS_X + (b * 32 + x) * 256 + t];
    ws[WS_PART + (b * 32 + x) * 256 + t] = xv * acc;
}

// ---------------------------------------------------------------- batchnorm
// 1 block, 256 threads (thread = k)
__global__ void tan_bn_kernel(float* ws, const float* gamma, const float* beta,
                              float* out) {
    int k = threadIdx.x;
    const float* part = ws + WS_PART;
    float lg[BB];
#pragma unroll
    for (int b = 0; b < BB; ++b) {
        float s = 0.f;
        for (int x = 0; x < 32; ++x) s += part[(b * 32 + x) * 256 + k];
        lg[b] = s;
    }
    float mean = 0.f;
#pragma unroll
    for (int b = 0; b < BB; ++b) mean += lg[b];
    mean *= 0.125f;
    float var = 0.f;
#pragma unroll
    for (int b = 0; b < BB; ++b) { float d = lg[b] - mean; var += d * d; }
    var *= 0.125f;
    float inv = rsqrtf(var + EPSV);
#pragma unroll
    for (int b = 0; b < BB; ++b)
        out[b * 256 + k] = (lg[b] - mean) * inv * gamma[k] + beta[k];
}

extern "C" void kernel_launch(void* const* d_in, const int* in_sizes, int n_in,
                              void* d_out, int out_size, void* d_ws, size_t ws_size,
                              hipStream_t stream) {
    (void)in_sizes; (void)n_in; (void)out_size; (void)ws_size;
    const float* x     = (const float*)d_in[0];
    const float* y     = (const float*)d_in[1];
    const float* z     = (const float*)d_in[2];
    const float* Vx    = (const float*)d_in[3];
    const float* gx    = (const float*)d_in[4];
    const float* bx    = (const float*)d_in[5];
    const float* Vy    = (const float*)d_in[6];
    const float* gy    = (const float*)d_in[7];
    const float* by    = (const float*)d_in[8];
    const float* Vz    = (const float*)d_in[9];
    const float* gz    = (const float*)d_in[10];
    const float* bz    = (const float*)d_in[11];
    const float* Vh    = (const float*)d_in[12];
    const float* gh    = (const float*)d_in[13];
    const float* bh    = (const float*)d_in[14];
    const float* gamma = (const float*)d_in[15];
    const float* beta  = (const float*)d_in[16];
    float* ws  = (float*)d_ws;
    float* out = (float*)d_out;

    tan_norm_kernel<<<4, 256, 0, stream>>>(Vx, Vy, Vz, Vh, ws);
    tan_proj_kernel<<<768, 256, 0, stream>>>(x, y, z, Vx, Vy, Vz,
                                             gx, gy, gz, bx, by, bz, ws);
    tan_score_kernel<<<128, 256, 0, stream>>>(Vh, gh, bh, ws);
    tan_softmax_kernel<<<16, 1024, 0, stream>>>(ws, out);
    tan_logits_kernel<<<256, 256, 0, stream>>>(ws, out);
    tan_bn_kernel<<<1, 256, 0, stream>>>(ws, gamma, beta, out);
}

// Round 2
// 181.948 us; speedup vs baseline: 1.4275x; 1.4275x over previous
//
#include <hip/hip_runtime.h>
#include <math.h>

#define BB 8
#define XD 32
#define DD 128
#define KK 256
#define HH 2
#define XYZ 32768
#define EPSV 1e-5f

// ws layout (float offsets)
#define WS_SS   0                     // 4 floats: sum-of-squares of Vx,Vy,Vz,Vh
#define WS_X    16                    // [B*32, 256] = 65536
#define WS_Y    (WS_X + 65536)
#define WS_Z    (WS_Y + 65536)
#define WS_RAW  (WS_Z + 65536)        // [B,H,XYZ] = 524288
#define WS_PART (WS_RAW + 524288)     // [B,32,256] = 65536

// ---------------------------------------------------------------- norms
__global__ void tan_norm_kernel(const float* Vx, const float* Vy,
                                const float* Vz, const float* Vh, float* ws) {
    __shared__ float red[256];
    int w = blockIdx.x;
    const float* p = (w == 0) ? Vx : (w == 1) ? Vy : (w == 2) ? Vz : Vh;
    int n = (w == 3) ? (HH * KK) : (KK * DD);
    float s = 0.f;
    for (int i = threadIdx.x; i < n; i += 256) { float v = p[i]; s += v * v; }
    red[threadIdx.x] = s;
    __syncthreads();
    for (int st = 128; st > 0; st >>= 1) {
        if (threadIdx.x < st) red[threadIdx.x] += red[threadIdx.x + st];
        __syncthreads();
    }
    if (threadIdx.x == 0) ws[WS_SS + w] = red[0];
}

// ---------------------------------------------------------------- projections
// grid 768: which = bid>>8 (0:x 1:y 2:z), row = bid&255 (b*32+i)
__global__ void tan_proj_kernel(const float* x, const float* y, const float* z,
                                const float* Vx, const float* Vy, const float* Vz,
                                const float* gx, const float* gy, const float* gz,
                                const float* bx, const float* by, const float* bz,
                                float* ws) {
    __shared__ float lin[DD];
    int bid = blockIdx.x;
    int which = bid >> 8;
    int row = bid & 255;
    const float *in, *V, *g, *bias;
    float* outp;
    if (which == 0)      { in = x; V = Vx; g = gx; bias = bx; outp = ws + WS_X; }
    else if (which == 1) { in = y; V = Vy; g = gy; bias = by; outp = ws + WS_Y; }
    else                 { in = z; V = Vz; g = gz; bias = bz; outp = ws + WS_Z; }
    float scale = g[0] * rsqrtf(ws[WS_SS + which]);
    int t = threadIdx.x;
    if (t < DD) lin[t] = in[row * DD + t];
    __syncthreads();
    const float4* v4 = (const float4*)(V + t * DD);
    const float4* l4 = (const float4*)lin;
    float acc = 0.f;
#pragma unroll 8
    for (int d4 = 0; d4 < DD / 4; ++d4) {
        float4 a = v4[d4];
        float4 b = l4[d4];
        acc += a.x * b.x + a.y * b.y + a.z * b.z + a.w * b.w;
    }
    float v = acc * scale + bias[t];
    outp[row * KK + t] = fmaxf(v, 0.f);
}

// ---------------------------------------------------------------- raw scores
// grid 256: one block per (b,x). 256 threads.
// att[b,h,x,y,z] = sum_k (sh*xhat[k]*Vh[h,k]) * yhat[y,k] * zhat[z,k]
// LDS: yhat/zhat [32][256] f32, XOR-swizzled at float4 granularity.
// Thread tile: y in {ty, ty+16}, z in {tz, tz+16}, both h  (8 outputs).
__global__ void __launch_bounds__(256)
tan_score_kernel(const float* Vh, const float* gh, const float* bh, float* ws) {
    __shared__ float ys[32 * 256];
    __shared__ float zs[32 * 256];
    int t = threadIdx.x;
    int bb = blockIdx.x >> 5;
    int xx = blockIdx.x & 31;
    const float* _xb = ws + WS_X + (bb * 32 + xx) * KK;
    const float* _yb = ws + WS_Y + bb * 8192;
    const float* _zb = ws + WS_Z + bb * 8192;
    float sh = gh[0] * rsqrtf(ws[WS_SS + 3]);

    // stage y/z with float4, swizzle group index by row&7
#pragma unroll
    for (int i = 0; i < 8; ++i) {
        int flat = i * 1024 + t * 4;
        int row = flat >> 8;
        int k = flat & 255;
        int gsw = (((k >> 2) ^ (row & 7)) << 2);
        *(float4*)(ys + row * 256 + gsw) = *(const float4*)(_yb + flat);
        *(float4*)(zs + row * 256 + gsw) = *(const float4*)(_zb + flat);
    }
    __syncthreads();

    int ty = t >> 4;          // 0..15
    int tz = t & 15;          // 0..15
    int y0 = ty, y1 = ty + 16;
    int z0 = tz, z1 = tz + 16;
    int ysw0 = (y0 & 7), ysw1 = (y1 & 7);
    int zsw0 = (z0 & 7), zsw1 = (z1 & 7);

    float a000 = 0.f, a001 = 0.f, a010 = 0.f, a011 = 0.f;
    float a100 = 0.f, a101 = 0.f, a110 = 0.f, a111 = 0.f;

#pragma unroll 4
    for (int kc = 0; kc < 256; kc += 4) {
        int g = kc >> 2;
        float4 xv  = *(const float4*)(_xb + kc);        // wave-uniform
        float4 vh0 = *(const float4*)(Vh + kc);         // wave-uniform
        float4 vh1 = *(const float4*)(Vh + KK + kc);    // wave-uniform
        float4 ya = *(const float4*)(ys + y0 * 256 + ((g ^ ysw0) << 2));
        float4 yb = *(const float4*)(ys + y1 * 256 + ((g ^ ysw1) << 2));
        float4 za = *(const float4*)(zs + z0 * 256 + ((g ^ zsw0) << 2));
        float4 zb = *(const float4*)(zs + z1 * 256 + ((g ^ zsw1) << 2));
#define TAN_STEP(c) { \
        float xs = sh * xv.c; \
        float w0 = xs * vh0.c, w1 = xs * vh1.c; \
        float t00 = w0 * ya.c, t01 = w0 * yb.c; \
        float t10 = w1 * ya.c, t11 = w1 * yb.c; \
        a000 = fmaf(t00, za.c, a000); a001 = fmaf(t00, zb.c, a001); \
        a010 = fmaf(t01, za.c, a010); a011 = fmaf(t01, zb.c, a011); \
        a100 = fmaf(t10, za.c, a100); a101 = fmaf(t10, zb.c, a101); \
        a110 = fmaf(t11, za.c, a110); a111 = fmaf(t11, zb.c, a111); }
        TAN_STEP(x) TAN_STEP(y) TAN_STEP(z) TAN_STEP(w)
#undef TAN_STEP
    }

    float b0 = bh[0], b1 = bh[1];
    float* r0 = ws + WS_RAW + (bb * 2 + 0) * XYZ + xx * 1024;
    float* r1 = r0 + XYZ;
    r0[y0 * 32 + z0] = a000 + b0;  r0[y0 * 32 + z1] = a001 + b0;
    r0[y1 * 32 + z0] = a010 + b0;  r0[y1 * 32 + z1] = a011 + b0;
    r1[y0 * 32 + z0] = a100 + b1;  r1[y0 * 32 + z1] = a101 + b1;
    r1[y1 * 32 + z0] = a110 + b1;  r1[y1 * 32 + z1] = a111 + b1;
}

// ---------------------------------------------------------------- softmax
// grid 16 (= b*2+h), 1024 threads; writes att to d_out + 2048
__global__ void tan_softmax_kernel(float* ws, float* out) {
    __shared__ float red[1024];
    int bh = blockIdx.x;
    const float* raw = ws + WS_RAW + bh * XYZ;
    float* att = out + BB * KK + bh * XYZ;
    int t = threadIdx.x;
    float m = -1e30f;
    for (int i = t; i < XYZ; i += 1024) m = fmaxf(m, raw[i]);
    red[t] = m;
    __syncthreads();
    for (int s = 512; s > 0; s >>= 1) {
        if (t < s) red[t] = fmaxf(red[t], red[t + s]);
        __syncthreads();
    }
    m = red[0];
    __syncthreads();
    float sum = 0.f;
    for (int i = t; i < XYZ; i += 1024) sum += expf(raw[i] - m);
    red[t] = sum;
    __syncthreads();
    for (int s = 512; s > 0; s >>= 1) {
        if (t < s) red[t] += red[t + s];
        __syncthreads();
    }
    float inv = 1.f / red[0];
    for (int i = t; i < XYZ; i += 1024) att[i] = expf(raw[i] - m) * inv;
}

// ---------------------------------------------------------------- logits partials
// grid 256: b = bid>>5, x = bid&31; 256 threads (thread = k)
__global__ void tan_logits_kernel(float* ws, const float* out) {
    __shared__ float lz[XD * KK];  // 32 KB: lz[z*256 + k]
    __shared__ float as[1024];     // att_sum[b,x,y,z] for this (b,x)
    int b = blockIdx.x >> 5;
    int x = blockIdx.x & 31;
    int t = threadIdx.x;
    const float* _zb = ws + WS_Z + b * 8192;
    for (int i = t; i < 8192; i += 256) lz[i] = _zb[i];
    const float* a0 = out + BB * KK + (b * 2) * XYZ + x * 1024;
    const float* a1 = a0 + XYZ;
    for (int i = t; i < 1024; i += 256) as[i] = a0[i] + a1[i];
    __syncthreads();
    const float* _yb = ws + WS_Y + b * 8192;
    float acc = 0.f;
    for (int y = 0; y < 32; ++y) {
        float s = 0.f;
        const float* ar = as + y * 32;
#pragma unroll
        for (int zi = 0; zi < 32; ++zi) s += ar[zi] * lz[zi * 256 + t];
        acc += _yb[y * 256 + t] * s;
    }
    float xv = ws[WS_X + (b * 32 + x) * 256 + t];
    ws[WS_PART + (b * 32 + x) * 256 + t] = xv * acc;
}

// ---------------------------------------------------------------- batchnorm
// 1 block, 256 threads (thread = k)
__global__ void tan_bn_kernel(float* ws, const float* gamma, const float* beta,
                              float* out) {
    int k = threadIdx.x;
    const float* part = ws + WS_PART;
    float lg[BB];
#pragma unroll
    for (int b = 0; b < BB; ++b) {
        float s = 0.f;
        for (int x = 0; x < 32; ++x) s += part[(b * 32 + x) * 256 + k];
        lg[b] = s;
    }
    float mean = 0.f;
#pragma unroll
    for (int b = 0; b < BB; ++b) mean += lg[b];
    mean *= 0.125f;
    float var = 0.f;
#pragma unroll
    for (int b = 0; b < BB; ++b) { float d = lg[b] - mean; var += d * d; }
    var *= 0.125f;
    float inv = rsqrtf(var + EPSV);
#pragma unroll
    for (int b = 0; b < BB; ++b)
        out[b * 256 + k] = (lg[b] - mean) * inv * gamma[k] + beta[k];
}

extern "C" void kernel_launch(void* const* d_in, const int* in_sizes, int n_in,
                              void* d_out, int out_size, void* d_ws, size_t ws_size,
                              hipStream_t stream) {
    (void)in_sizes; (void)n_in; (void)out_size; (void)ws_size;
    const float* x     = (const float*)d_in[0];
    const float* y     = (const float*)d_in[1];
    const float* z     = (const float*)d_in[2];
    const float* Vx    = (const float*)d_in[3];
    const float* gx    = (const float*)d_in[4];
    const float* bx    = (const float*)d_in[5];
    const float* Vy    = (const float*)d_in[6];
    const float* gy    = (const float*)d_in[7];
    const float* by    = (const float*)d_in[8];
    const float* Vz    = (const float*)d_in[9];
    const float* gz    = (const float*)d_in[10];
    const float* bz    = (const float*)d_in[11];
    const float* Vh    = (const float*)d_in[12];
    const float* gh    = (const float*)d_in[13];
    const float* bh    = (const float*)d_in[14];
    const float* gamma = (const float*)d_in[15];
    const float* beta  = (const float*)d_in[16];
    float* ws  = (float*)d_ws;
    float* out = (float*)d_out;

    tan_norm_kernel<<<4, 256, 0, stream>>>(Vx, Vy, Vz, Vh, ws);
    tan_proj_kernel<<<768, 256, 0, stream>>>(x, y, z, Vx, Vy, Vz,
                                             gx, gy, gz, bx, by, bz, ws);
    tan_score_kernel<<<256, 256, 0, stream>>>(Vh, gh, bh, ws);
    tan_softmax_kernel<<<16, 1024, 0, stream>>>(ws, out);
    tan_logits_kernel<<<256, 256, 0, stream>>>(ws, out);
    tan_bn_kernel<<<1, 256, 0, stream>>>(ws, gamma, beta, out);
}

// Round 3
// 149.621 us; speedup vs baseline: 1.7359x; 1.2161x over previous
//
#include <hip/hip_runtime.h>
#include <math.h>

#define BB 8
#define XD 32
#define DD 128
#define KK 256
#define HH 2
#define XYZ 32768
#define EPSV 1e-5f

// ws layout (float offsets)
#define WS_SS   0                     // 64 floats: 4 weights x 16 partial sum-of-squares
#define WS_X    64                    // [B*32, 256] = 65536
#define WS_Y    (WS_X + 65536)
#define WS_Z    (WS_Y + 65536)
#define WS_RAW  (WS_Z + 65536)        // [B,H,XYZ] = 524288
#define WS_PART (WS_RAW + 524288)     // [B,32,256] = 65536

// ---------------------------------------------------------------- norms
// grid 64: w = bid>>4 (0:Vx 1:Vy 2:Vz 3:Vh), chunk = bid&15 (512 float4 each)
__global__ void tan_norm_kernel(const float* Vx, const float* Vy,
                                const float* Vz, const float* Vh, float* ws) {
    __shared__ float red[256];
    int w = blockIdx.x >> 4;
    int c = blockIdx.x & 15;
    const float* p = (w == 0) ? Vx : (w == 1) ? Vy : (w == 2) ? Vz : Vh;
    int n4 = (w == 3) ? 128 : 8192;   // total float4 count
    const float4* p4 = (const float4*)p;
    float s = 0.f;
#pragma unroll
    for (int r = 0; r < 2; ++r) {
        int i4 = c * 512 + r * 256 + threadIdx.x;
        if (i4 < n4) {
            float4 v = p4[i4];
            s += v.x * v.x + v.y * v.y + v.z * v.z + v.w * v.w;
        }
    }
    red[threadIdx.x] = s;
    __syncthreads();
    for (int st = 128; st > 0; st >>= 1) {
        if (threadIdx.x < st) red[threadIdx.x] += red[threadIdx.x + st];
        __syncthreads();
    }
    if (threadIdx.x == 0) ws[WS_SS + w * 16 + c] = red[0];
}

__device__ __forceinline__ float tan_ss(const float* ws, int which) {
    float s = 0.f;
#pragma unroll
    for (int i = 0; i < 16; ++i) s += ws[WS_SS + which * 16 + i];
    return s;
}

// ---------------------------------------------------------------- projections
// grid 768: which = bid>>8 (0:x 1:y 2:z), row = bid&255 (b*32+i)
__global__ void tan_proj_kernel(const float* x, const float* y, const float* z,
                                const float* Vx, const float* Vy, const float* Vz,
                                const float* gx, const float* gy, const float* gz,
                                const float* bx, const float* by, const float* bz,
                                float* ws) {
    __shared__ float lin[DD];
    int bid = blockIdx.x;
    int which = bid >> 8;
    int row = bid & 255;
    const float *in, *V, *g, *bias;
    float* outp;
    if (which == 0)      { in = x; V = Vx; g = gx; bias = bx; outp = ws + WS_X; }
    else if (which == 1) { in = y; V = Vy; g = gy; bias = by; outp = ws + WS_Y; }
    else                 { in = z; V = Vz; g = gz; bias = bz; outp = ws + WS_Z; }
    float scale = g[0] * rsqrtf(tan_ss(ws, which));
    int t = threadIdx.x;
    if (t < DD) lin[t] = in[row * DD + t];
    __syncthreads();
    const float4* v4 = (const float4*)(V + t * DD);
    const float4* l4 = (const float4*)lin;
    float acc = 0.f;
#pragma unroll 8
    for (int d4 = 0; d4 < DD / 4; ++d4) {
        float4 a = v4[d4];
        float4 b = l4[d4];
        acc += a.x * b.x + a.y * b.y + a.z * b.z + a.w * b.w;
    }
    float v = acc * scale + bias[t];
    outp[row * KK + t] = fmaxf(v, 0.f);
}

// ---------------------------------------------------------------- raw scores
// grid 256: one block per (b,x). 256 threads.
__global__ void __launch_bounds__(256)
tan_score_kernel(const float* Vh, const float* gh, const float* bh, float* ws) {
    __shared__ float ys[32 * 256];
    __shared__ float zs[32 * 256];
    int t = threadIdx.x;
    int bb = blockIdx.x >> 5;
    int xx = blockIdx.x & 31;
    const float* _xb = ws + WS_X + (bb * 32 + xx) * KK;
    const float* _yb = ws + WS_Y + bb * 8192;
    const float* _zb = ws + WS_Z + bb * 8192;
    float sh = gh[0] * rsqrtf(tan_ss(ws, 3));

#pragma unroll
    for (int i = 0; i < 8; ++i) {
        int flat = i * 1024 + t * 4;
        int row = flat >> 8;
        int k = flat & 255;
        int gsw = (((k >> 2) ^ (row & 7)) << 2);
        *(float4*)(ys + row * 256 + gsw) = *(const float4*)(_yb + flat);
        *(float4*)(zs + row * 256 + gsw) = *(const float4*)(_zb + flat);
    }
    __syncthreads();

    int ty = t >> 4;
    int tz = t & 15;
    int y0 = ty, y1 = ty + 16;
    int z0 = tz, z1 = tz + 16;
    int ysw0 = (y0 & 7), ysw1 = (y1 & 7);
    int zsw0 = (z0 & 7), zsw1 = (z1 & 7);

    float a000 = 0.f, a001 = 0.f, a010 = 0.f, a011 = 0.f;
    float a100 = 0.f, a101 = 0.f, a110 = 0.f, a111 = 0.f;

#pragma unroll 4
    for (int kc = 0; kc < 256; kc += 4) {
        int g = kc >> 2;
        float4 xv  = *(const float4*)(_xb + kc);
        float4 vh0 = *(const float4*)(Vh + kc);
        float4 vh1 = *(const float4*)(Vh + KK + kc);
        float4 ya = *(const float4*)(ys + y0 * 256 + ((g ^ ysw0) << 2));
        float4 yb = *(const float4*)(ys + y1 * 256 + ((g ^ ysw1) << 2));
        float4 za = *(const float4*)(zs + z0 * 256 + ((g ^ zsw0) << 2));
        float4 zb = *(const float4*)(zs + z1 * 256 + ((g ^ zsw1) << 2));
#define TAN_STEP(c) { \
        float xs = sh * xv.c; \
        float w0 = xs * vh0.c, w1 = xs * vh1.c; \
        float t00 = w0 * ya.c, t01 = w0 * yb.c; \
        float t10 = w1 * ya.c, t11 = w1 * yb.c; \
        a000 = fmaf(t00, za.c, a000); a001 = fmaf(t00, zb.c, a001); \
        a010 = fmaf(t01, za.c, a010); a011 = fmaf(t01, zb.c, a011); \
        a100 = fmaf(t10, za.c, a100); a101 = fmaf(t10, zb.c, a101); \
        a110 = fmaf(t11, za.c, a110); a111 = fmaf(t11, zb.c, a111); }
        TAN_STEP(x) TAN_STEP(y) TAN_STEP(z) TAN_STEP(w)
#undef TAN_STEP
    }

    float b0 = bh[0], b1 = bh[1];
    float* r0 = ws + WS_RAW + (bb * 2 + 0) * XYZ + xx * 1024;
    float* r1 = r0 + XYZ;
    r0[y0 * 32 + z0] = a000 + b0;  r0[y0 * 32 + z1] = a001 + b0;
    r0[y1 * 32 + z0] = a010 + b0;  r0[y1 * 32 + z1] = a011 + b0;
    r1[y0 * 32 + z0] = a100 + b1;  r1[y0 * 32 + z1] = a101 + b1;
    r1[y1 * 32 + z0] = a110 + b1;  r1[y1 * 32 + z1] = a111 + b1;
}

// ---------------------------------------------------------------- softmax
// grid 16 (= b*2+h), 1024 threads; online max+sum (1 read), then write pass.
__global__ void tan_softmax_kernel(float* ws, float* out) {
    __shared__ float rm[1024];
    __shared__ float rl[1024];
    int bh = blockIdx.x;
    const float* raw = ws + WS_RAW + bh * XYZ;
    float* att = out + BB * KK + bh * XYZ;
    int t = threadIdx.x;
    float m = -1e30f, l = 0.f;
    for (int i = t; i < XYZ; i += 1024) {
        float v = raw[i];
        float nm = fmaxf(m, v);
        l = l * __expf(m - nm) + __expf(v - nm);
        m = nm;
    }
    rm[t] = m; rl[t] = l;
    __syncthreads();
    for (int s = 512; s > 0; s >>= 1) {
        if (t < s) {
            float m2 = rm[t + s], l2 = rl[t + s];
            float m1 = rm[t], l1 = rl[t];
            float nm = fmaxf(m1, m2);
            rl[t] = l1 * __expf(m1 - nm) + l2 * __expf(m2 - nm);
            rm[t] = nm;
        }
        __syncthreads();
    }
    float M = rm[0];
    float inv = 1.f / rl[0];
    for (int i = t; i < XYZ; i += 1024) att[i] = __expf(raw[i] - M) * inv;
}

// ---------------------------------------------------------------- logits partials
// grid 256: b = bid>>5, x = bid&31; 256 threads (thread = k)
__global__ void tan_logits_kernel(float* ws, const float* out) {
    __shared__ float lz[XD * KK];
    __shared__ float as[1024];
    int b = blockIdx.x >> 5;
    int x = blockIdx.x & 31;
    int t = threadIdx.x;
    const float* _zb = ws + WS_Z + b * 8192;
    for (int i = t; i < 8192; i += 256) lz[i] = _zb[i];
    const float* a0 = out + BB * KK + (b * 2) * XYZ + x * 1024;
    const float* a1 = a0 + XYZ;
    for (int i = t; i < 1024; i += 256) as[i] = a0[i] + a1[i];
    __syncthreads();
    const float* _yb = ws + WS_Y + b * 8192;
    float acc = 0.f;
    for (int y = 0; y < 32; ++y) {
        float s = 0.f;
        const float* ar = as + y * 32;
#pragma unroll
        for (int zi = 0; zi < 32; ++zi) s += ar[zi] * lz[zi * 256 + t];
        acc += _yb[y * 256 + t] * s;
    }
    float xv = ws[WS_X + (b * 32 + x) * 256 + t];
    ws[WS_PART + (b * 32 + x) * 256 + t] = xv * acc;
}

// ---------------------------------------------------------------- batchnorm
// 1 block, 256 threads (thread = k)
__global__ void tan_bn_kernel(float* ws, const float* gamma, const float* beta,
                              float* out) {
    int k = threadIdx.x;
    const float* part = ws + WS_PART;
    float lg[BB];
#pragma unroll
    for (int b = 0; b < BB; ++b) {
        float s = 0.f;
        for (int x = 0; x < 32; ++x) s += part[(b * 32 + x) * 256 + k];
        lg[b] = s;
    }
    float mean = 0.f;
#pragma unroll
    for (int b = 0; b < BB; ++b) mean += lg[b];
    mean *= 0.125f;
    float var = 0.f;
#pragma unroll
    for (int b = 0; b < BB; ++b) { float d = lg[b] - mean; var += d * d; }
    var *= 0.125f;
    float inv = rsqrtf(var + EPSV);
#pragma unroll
    for (int b = 0; b < BB; ++b)
        out[b * 256 + k] = (lg[b] - mean) * inv * gamma[k] + beta[k];
}

extern "C" void kernel_launch(void* const* d_in, const int* in_sizes, int n_in,
                              void* d_out, int out_size, void* d_ws, size_t ws_size,
                              hipStream_t stream) {
    (void)in_sizes; (void)n_in; (void)out_size; (void)ws_size;
    const float* x     = (const float*)d_in[0];
    const float* y     = (const float*)d_in[1];
    const float* z     = (const float*)d_in[2];
    const float* Vx    = (const float*)d_in[3];
    const float* gx    = (const float*)d_in[4];
    const float* bx    = (const float*)d_in[5];
    const float* Vy    = (const float*)d_in[6];
    const float* gy    = (const float*)d_in[7];
    const float* by    = (const float*)d_in[8];
    const float* Vz    = (const float*)d_in[9];
    const float* gz    = (const float*)d_in[10];
    const float* bz    = (const float*)d_in[11];
    const float* Vh    = (const float*)d_in[12];
    const float* gh    = (const float*)d_in[13];
    const float* bh    = (const float*)d_in[14];
    const float* gamma = (const float*)d_in[15];
    const float* beta  = (const float*)d_in[16];
    float* ws  = (float*)d_ws;
    float* out = (float*)d_out;

    tan_norm_kernel<<<64, 256, 0, stream>>>(Vx, Vy, Vz, Vh, ws);
    tan_proj_kernel<<<768, 256, 0, stream>>>(x, y, z, Vx, Vy, Vz,
                                             gx, gy, gz, bx, by, bz, ws);
    tan_score_kernel<<<256, 256, 0, stream>>>(Vh, gh, bh, ws);
    tan_softmax_kernel<<<16, 1024, 0, stream>>>(ws, out);
    tan_logits_kernel<<<256, 256, 0, stream>>>(ws, out);
    tan_bn_kernel<<<1, 256, 0, stream>>>(ws, gamma, beta, out);
}

// Round 4
// 129.175 us; speedup vs baseline: 2.0107x; 1.1583x over previous
//
#include <hip/hip_runtime.h>
#include <math.h>

#define BB 8
#define XD 32
#define DD 128
#define KK 256
#define HH 2
#define XYZ 32768
#define EPSV 1e-5f

// ws layout (float offsets)
#define WS_X    0                     // [B*32, 256] = 65536
#define WS_Y    65536
#define WS_Z    131072
#define WS_RAW  196608                // [B,H,XYZ] = 524288
#define WS_PART (WS_RAW + 524288)     // [B,32,256] = 65536

// ---------------------------------------------------------------- projections
// grid 192: which = bid/64 (0:x 1:y 2:z), rgrp = bid%64 -> 4 global rows.
// Each thread t computes feature k=t for 4 rows; V-row t read once (float4),
// reused 4x; ||V||^2 computed inline (wave shfl + LDS combine).
__global__ void __launch_bounds__(256)
tan_proj_kernel(const float* x, const float* y, const float* z,
                const float* Vx, const float* Vy, const float* Vz,
                const float* gx, const float* gy, const float* gz,
                const float* bx, const float* by, const float* bz,
                float* ws) {
    __shared__ float lin[4 * DD];
    __shared__ float wred[4];
    int bid = blockIdx.x;
    int which = bid >> 6;
    int rgrp = bid & 63;
    int r0 = rgrp * 4;
    const float *in, *V, *g, *bias;
    float* outp;
    if (which == 0)      { in = x; V = Vx; g = gx; bias = bx; outp = ws + WS_X; }
    else if (which == 1) { in = y; V = Vy; g = gy; bias = by; outp = ws + WS_Y; }
    else                 { in = z; V = Vz; g = gz; bias = bz; outp = ws + WS_Z; }
    int t = threadIdx.x;
    // stage 4 input rows (coalesced)
    {
        int f0 = t, f1 = t + 256;
        lin[f0] = in[(r0 + (f0 >> 7)) * DD + (f0 & 127)];
        lin[f1] = in[(r0 + (f1 >> 7)) * DD + (f1 & 127)];
    }
    __syncthreads();
    const float4* v4 = (const float4*)(V + t * DD);
    const float4* l4 = (const float4*)lin;
    float a0 = 0.f, a1 = 0.f, a2 = 0.f, a3 = 0.f, ssp = 0.f;
#pragma unroll 8
    for (int d4 = 0; d4 < DD / 4; ++d4) {
        float4 a = v4[d4];
        ssp += a.x * a.x + a.y * a.y + a.z * a.z + a.w * a.w;
        float4 b0 = l4[d4];
        float4 b1 = l4[32 + d4];
        float4 b2 = l4[64 + d4];
        float4 b3 = l4[96 + d4];
        a0 += a.x * b0.x + a.y * b0.y + a.z * b0.z + a.w * b0.w;
        a1 += a.x * b1.x + a.y * b1.y + a.z * b1.z + a.w * b1.w;
        a2 += a.x * b2.x + a.y * b2.y + a.z * b2.z + a.w * b2.w;
        a3 += a.x * b3.x + a.y * b3.y + a.z * b3.z + a.w * b3.w;
    }
#pragma unroll
    for (int o = 32; o > 0; o >>= 1) ssp += __shfl_xor(ssp, o);
    if ((t & 63) == 0) wred[t >> 6] = ssp;
    __syncthreads();
    float ss = wred[0] + wred[1] + wred[2] + wred[3];
    float scale = g[0] * rsqrtf(ss);
    float bv = bias[t];
    outp[(r0 + 0) * KK + t] = fmaxf(a0 * scale + bv, 0.f);
    outp[(r0 + 1) * KK + t] = fmaxf(a1 * scale + bv, 0.f);
    outp[(r0 + 2) * KK + t] = fmaxf(a2 * scale + bv, 0.f);
    outp[(r0 + 3) * KK + t] = fmaxf(a3 * scale + bv, 0.f);
}

// ---------------------------------------------------------------- raw scores
// grid 256: one block per (b,x). 256 threads. ||Vh||^2 computed inline.
__global__ void __launch_bounds__(256)
tan_score_kernel(const float* Vh, const float* gh, const float* bh, float* ws) {
    __shared__ float ys[32 * 256];
    __shared__ float zs[32 * 256];
    __shared__ float shh;
    int t = threadIdx.x;
    int bb = blockIdx.x >> 5;
    int xx = blockIdx.x & 31;
    const float* _xb = ws + WS_X + (bb * 32 + xx) * KK;
    const float* _yb = ws + WS_Y + bb * 8192;
    const float* _zb = ws + WS_Z + bb * 8192;

    if (t < 64) {
        float4 h1 = *(const float4*)(Vh + t * 8);
        float4 h2 = *(const float4*)(Vh + t * 8 + 4);
        float hs = h1.x * h1.x + h1.y * h1.y + h1.z * h1.z + h1.w * h1.w
                 + h2.x * h2.x + h2.y * h2.y + h2.z * h2.z + h2.w * h2.w;
#pragma unroll
        for (int o = 32; o > 0; o >>= 1) hs += __shfl_xor(hs, o);
        if (t == 0) shh = hs;
    }

#pragma unroll
    for (int i = 0; i < 8; ++i) {
        int flat = i * 1024 + t * 4;
        int row = flat >> 8;
        int k = flat & 255;
        int gsw = (((k >> 2) ^ (row & 7)) << 2);
        *(float4*)(ys + row * 256 + gsw) = *(const float4*)(_yb + flat);
        *(float4*)(zs + row * 256 + gsw) = *(const float4*)(_zb + flat);
    }
    __syncthreads();
    float sh = gh[0] * rsqrtf(shh);

    int ty = t >> 4;
    int tz = t & 15;
    int y0 = ty, y1 = ty + 16;
    int z0 = tz, z1 = tz + 16;
    int ysw0 = (y0 & 7), ysw1 = (y1 & 7);
    int zsw0 = (z0 & 7), zsw1 = (z1 & 7);

    float a000 = 0.f, a001 = 0.f, a010 = 0.f, a011 = 0.f;
    float a100 = 0.f, a101 = 0.f, a110 = 0.f, a111 = 0.f;

#pragma unroll 4
    for (int kc = 0; kc < 256; kc += 4) {
        int g = kc >> 2;
        float4 xv  = *(const float4*)(_xb + kc);
        float4 vh0 = *(const float4*)(Vh + kc);
        float4 vh1 = *(const float4*)(Vh + KK + kc);
        float4 ya = *(const float4*)(ys + y0 * 256 + ((g ^ ysw0) << 2));
        float4 yb = *(const float4*)(ys + y1 * 256 + ((g ^ ysw1) << 2));
        float4 za = *(const float4*)(zs + z0 * 256 + ((g ^ zsw0) << 2));
        float4 zb = *(const float4*)(zs + z1 * 256 + ((g ^ zsw1) << 2));
#define TAN_STEP(c) { \
        float xs = sh * xv.c; \
        float w0 = xs * vh0.c, w1 = xs * vh1.c; \
        float t00 = w0 * ya.c, t01 = w0 * yb.c; \
        float t10 = w1 * ya.c, t11 = w1 * yb.c; \
        a000 = fmaf(t00, za.c, a000); a001 = fmaf(t00, zb.c, a001); \
        a010 = fmaf(t01, za.c, a010); a011 = fmaf(t01, zb.c, a011); \
        a100 = fmaf(t10, za.c, a100); a101 = fmaf(t10, zb.c, a101); \
        a110 = fmaf(t11, za.c, a110); a111 = fmaf(t11, zb.c, a111); }
        TAN_STEP(x) TAN_STEP(y) TAN_STEP(z) TAN_STEP(w)
#undef TAN_STEP
    }

    float b0 = bh[0], b1 = bh[1];
    float* r0 = ws + WS_RAW + (bb * 2 + 0) * XYZ + xx * 1024;
    float* r1 = r0 + XYZ;
    r0[y0 * 32 + z0] = a000 + b0;  r0[y0 * 32 + z1] = a001 + b0;
    r0[y1 * 32 + z0] = a010 + b0;  r0[y1 * 32 + z1] = a011 + b0;
    r1[y0 * 32 + z0] = a100 + b1;  r1[y0 * 32 + z1] = a101 + b1;
    r1[y1 * 32 + z0] = a110 + b1;  r1[y1 * 32 + z1] = a111 + b1;
}

// ---------------------------------------------------------------- softmax
// grid 16 (= b*2+h), 1024 threads; all 32 elems/thread held in registers:
// one global read, one global write.
__global__ void __launch_bounds__(1024)
tan_softmax_kernel(float* ws, float* out) {
    __shared__ float red[1024];
    int bh = blockIdx.x;
    int t = threadIdx.x;
    const float4* raw4 = (const float4*)(ws + WS_RAW + bh * XYZ);
    float4* att4 = (float4*)(out + BB * KK + bh * XYZ);
    float4 v[8];
#pragma unroll
    for (int i = 0; i < 8; ++i) v[i] = raw4[i * 1024 + t];
    float m = -1e30f;
#pragma unroll
    for (int i = 0; i < 8; ++i)
        m = fmaxf(m, fmaxf(fmaxf(v[i].x, v[i].y), fmaxf(v[i].z, v[i].w)));
    red[t] = m;
    __syncthreads();
    for (int s = 512; s > 0; s >>= 1) {
        if (t < s) red[t] = fmaxf(red[t], red[t + s]);
        __syncthreads();
    }
    float M = red[0];
    __syncthreads();
    float l = 0.f;
#pragma unroll
    for (int i = 0; i < 8; ++i) {
        v[i].x = __expf(v[i].x - M); v[i].y = __expf(v[i].y - M);
        v[i].z = __expf(v[i].z - M); v[i].w = __expf(v[i].w - M);
        l += v[i].x + v[i].y + v[i].z + v[i].w;
    }
    red[t] = l;
    __syncthreads();
    for (int s = 512; s > 0; s >>= 1) {
        if (t < s) red[t] += red[t + s];
        __syncthreads();
    }
    float inv = 1.f / red[0];
#pragma unroll
    for (int i = 0; i < 8; ++i) {
        float4 o = v[i];
        o.x *= inv; o.y *= inv; o.z *= inv; o.w *= inv;
        att4[i * 1024 + t] = o;
    }
}

// ---------------------------------------------------------------- logits partials
// grid 256: b = bid>>5, x = bid&31; 256 threads (thread = k).
// zhat column held in 32 registers; att_sum rows read as broadcast float4.
__global__ void __launch_bounds__(256)
tan_logits_kernel(float* ws, const float* out) {
    __shared__ float as4[1024];
    int b = blockIdx.x >> 5;
    int x = blockIdx.x & 31;
    int t = threadIdx.x;
    const float* _zb = ws + WS_Z + b * 8192;
    float zreg[32];
#pragma unroll
    for (int zi = 0; zi < 32; ++zi) zreg[zi] = _zb[zi * 256 + t];
    const float* a0 = out + BB * KK + (b * 2) * XYZ + x * 1024;
    const float* a1 = a0 + XYZ;
    for (int i = t; i < 1024; i += 256) as4[i] = a0[i] + a1[i];
    __syncthreads();
    const float* _yb = ws + WS_Y + b * 8192;
    float acc = 0.f;
#pragma unroll 4
    for (int y = 0; y < 32; ++y) {
        float s = 0.f;
        const float4* ar = (const float4*)(as4 + y * 32);
#pragma unroll
        for (int j = 0; j < 8; ++j) {
            float4 a = ar[j];
            s += a.x * zreg[j * 4] + a.y * zreg[j * 4 + 1]
               + a.z * zreg[j * 4 + 2] + a.w * zreg[j * 4 + 3];
        }
        acc = fmaf(_yb[y * 256 + t], s, acc);
    }
    float xv = ws[WS_X + (b * 32 + x) * 256 + t];
    ws[WS_PART + (b * 32 + x) * 256 + t] = xv * acc;
}

// ---------------------------------------------------------------- batchnorm
// 1 block, 1024 threads: tg = t>>8 sums 8 x-slices; LDS combine; tg 0 writes.
__global__ void __launch_bounds__(1024)
tan_bn_kernel(float* ws, const float* gamma, const float* beta, float* out) {
    __shared__ float red[8192];
    int t = threadIdx.x;
    int tg = t >> 8;
    int k = t & 255;
    const float* part = ws + WS_PART;
    float lg[BB];
#pragma unroll
    for (int b = 0; b < BB; ++b) {
        float s = 0.f;
#pragma unroll
        for (int xi = 0; xi < 8; ++xi)
            s += part[(b * 32 + tg * 8 + xi) * 256 + k];
        red[tg * 2048 + b * 256 + k] = s;
    }
    __syncthreads();
    if (tg == 0) {
#pragma unroll
        for (int b = 0; b < BB; ++b)
            lg[b] = red[b * 256 + k] + red[2048 + b * 256 + k]
                  + red[4096 + b * 256 + k] + red[6144 + b * 256 + k];
        float mean = 0.f;
#pragma unroll
        for (int b = 0; b < BB; ++b) mean += lg[b];
        mean *= 0.125f;
        float var = 0.f;
#pragma unroll
        for (int b = 0; b < BB; ++b) { float d = lg[b] - mean; var += d * d; }
        var *= 0.125f;
        float inv = rsqrtf(var + EPSV);
        float gm = gamma[k], bt = beta[k];
#pragma unroll
        for (int b = 0; b < BB; ++b)
            out[b * 256 + k] = (lg[b] - mean) * inv * gm + bt;
    }
}

extern "C" void kernel_launch(void* const* d_in, const int* in_sizes, int n_in,
                              void* d_out, int out_size, void* d_ws, size_t ws_size,
                              hipStream_t stream) {
    (void)in_sizes; (void)n_in; (void)out_size; (void)ws_size;
    const float* x     = (const float*)d_in[0];
    const float* y     = (const float*)d_in[1];
    const float* z     = (const float*)d_in[2];
    const float* Vx    = (const float*)d_in[3];
    const float* gx    = (const float*)d_in[4];
    const float* bx    = (const float*)d_in[5];
    const float* Vy    = (const float*)d_in[6];
    const float* gy    = (const float*)d_in[7];
    const float* by    = (const float*)d_in[8];
    const float* Vz    = (const float*)d_in[9];
    const float* gz    = (const float*)d_in[10];
    const float* bz    = (const float*)d_in[11];
    const float* Vh    = (const float*)d_in[12];
    const float* gh    = (const float*)d_in[13];
    const float* bh    = (const float*)d_in[14];
    const float* gamma = (const float*)d_in[15];
    const float* beta  = (const float*)d_in[16];
    float* ws  = (float*)d_ws;
    float* out = (float*)d_out;

    tan_proj_kernel<<<192, 256, 0, stream>>>(x, y, z, Vx, Vy, Vz,
                                             gx, gy, gz, bx, by, bz, ws);
    tan_score_kernel<<<256, 256, 0, stream>>>(Vh, gh, bh, ws);
    tan_softmax_kernel<<<16, 1024, 0, stream>>>(ws, out);
    tan_logits_kernel<<<256, 256, 0, stream>>>(ws, out);
    tan_bn_kernel<<<1, 1024, 0, stream>>>(ws, gamma, beta, out);
}

// Round 5
// 121.733 us; speedup vs baseline: 2.1336x; 1.0611x over previous
//
#include <hip/hip_runtime.h>
#include <math.h>

#define BB 8
#define XD 32
#define DD 128
#define KK 256
#define HH 2
#define XYZ 32768
#define EPSV 1e-5f

// ws layout (float offsets)
#define WS_X    0                     // [B*32, 256] = 65536
#define WS_Y    65536
#define WS_Z    131072
#define WS_RAW  196608                // [B,H,XYZ] = 524288
#define WS_SM   (WS_RAW + 524288)     // [B,32,4] partial (m0,l0,m1,l1) = 1024
#define WS_LOG  (WS_SM + 1024)        // [B,256] logits accumulator = 2048 (memset 0)

// ---------------------------------------------------------------- projections
// grid 192: which = bid/64 (0:x 1:y 2:z), rgrp = bid%64 -> 4 global rows.
__global__ void __launch_bounds__(256)
tan_proj_kernel(const float* x, const float* y, const float* z,
                const float* Vx, const float* Vy, const float* Vz,
                const float* gx, const float* gy, const float* gz,
                const float* bx, const float* by, const float* bz,
                float* ws) {
    __shared__ float lin[4 * DD];
    __shared__ float wred[4];
    int bid = blockIdx.x;
    int which = bid >> 6;
    int rgrp = bid & 63;
    int r0 = rgrp * 4;
    const float *in, *V, *g, *bias;
    float* outp;
    if (which == 0)      { in = x; V = Vx; g = gx; bias = bx; outp = ws + WS_X; }
    else if (which == 1) { in = y; V = Vy; g = gy; bias = by; outp = ws + WS_Y; }
    else                 { in = z; V = Vz; g = gz; bias = bz; outp = ws + WS_Z; }
    int t = threadIdx.x;
    {
        int f0 = t, f1 = t + 256;
        lin[f0] = in[(r0 + (f0 >> 7)) * DD + (f0 & 127)];
        lin[f1] = in[(r0 + (f1 >> 7)) * DD + (f1 & 127)];
    }
    __syncthreads();
    const float4* v4 = (const float4*)(V + t * DD);
    const float4* l4 = (const float4*)lin;
    float a0 = 0.f, a1 = 0.f, a2 = 0.f, a3 = 0.f, ssp = 0.f;
#pragma unroll 8
    for (int d4 = 0; d4 < DD / 4; ++d4) {
        float4 a = v4[d4];
        ssp += a.x * a.x + a.y * a.y + a.z * a.z + a.w * a.w;
        float4 b0 = l4[d4];
        float4 b1 = l4[32 + d4];
        float4 b2 = l4[64 + d4];
        float4 b3 = l4[96 + d4];
        a0 += a.x * b0.x + a.y * b0.y + a.z * b0.z + a.w * b0.w;
        a1 += a.x * b1.x + a.y * b1.y + a.z * b1.z + a.w * b1.w;
        a2 += a.x * b2.x + a.y * b2.y + a.z * b2.z + a.w * b2.w;
        a3 += a.x * b3.x + a.y * b3.y + a.z * b3.z + a.w * b3.w;
    }
#pragma unroll
    for (int o = 32; o > 0; o >>= 1) ssp += __shfl_xor(ssp, o);
    if ((t & 63) == 0) wred[t >> 6] = ssp;
    __syncthreads();
    float ss = wred[0] + wred[1] + wred[2] + wred[3];
    float scale = g[0] * rsqrtf(ss);
    float bv = bias[t];
    outp[(r0 + 0) * KK + t] = fmaxf(a0 * scale + bv, 0.f);
    outp[(r0 + 1) * KK + t] = fmaxf(a1 * scale + bv, 0.f);
    outp[(r0 + 2) * KK + t] = fmaxf(a2 * scale + bv, 0.f);
    outp[(r0 + 3) * KK + t] = fmaxf(a3 * scale + bv, 0.f);
}

// ---------------------------------------------------------------- raw scores
// grid 256: one block per (b,x). Also emits per-(b,x) online-softmax partials.
__global__ void __launch_bounds__(256)
tan_score_kernel(const float* Vh, const float* gh, const float* bh, float* ws) {
    __shared__ float ys[32 * 256];
    __shared__ float zs[32 * 256];
    __shared__ float shh;
    __shared__ float smred[4][4];
    int t = threadIdx.x;
    int bb = blockIdx.x >> 5;
    int xx = blockIdx.x & 31;
    const float* _xb = ws + WS_X + (bb * 32 + xx) * KK;
    const float* _yb = ws + WS_Y + bb * 8192;
    const float* _zb = ws + WS_Z + bb * 8192;

    if (t < 64) {
        float4 h1 = *(const float4*)(Vh + t * 8);
        float4 h2 = *(const float4*)(Vh + t * 8 + 4);
        float hs = h1.x * h1.x + h1.y * h1.y + h1.z * h1.z + h1.w * h1.w
                 + h2.x * h2.x + h2.y * h2.y + h2.z * h2.z + h2.w * h2.w;
#pragma unroll
        for (int o = 32; o > 0; o >>= 1) hs += __shfl_xor(hs, o);
        if (t == 0) shh = hs;
    }

#pragma unroll
    for (int i = 0; i < 8; ++i) {
        int flat = i * 1024 + t * 4;
        int row = flat >> 8;
        int k = flat & 255;
        int gsw = (((k >> 2) ^ (row & 7)) << 2);
        *(float4*)(ys + row * 256 + gsw) = *(const float4*)(_yb + flat);
        *(float4*)(zs + row * 256 + gsw) = *(const float4*)(_zb + flat);
    }
    __syncthreads();
    float sh = gh[0] * rsqrtf(shh);

    int ty = t >> 4;
    int tz = t & 15;
    int y0 = ty, y1 = ty + 16;
    int z0 = tz, z1 = tz + 15 + 1;
    int ysw0 = (y0 & 7), ysw1 = (y1 & 7);
    int zsw0 = (z0 & 7), zsw1 = (z1 & 7);

    float a000 = 0.f, a001 = 0.f, a010 = 0.f, a011 = 0.f;
    float a100 = 0.f, a101 = 0.f, a110 = 0.f, a111 = 0.f;

#pragma unroll 4
    for (int kc = 0; kc < 256; kc += 4) {
        int g = kc >> 2;
        float4 xv  = *(const float4*)(_xb + kc);
        float4 vh0 = *(const float4*)(Vh + kc);
        float4 vh1 = *(const float4*)(Vh + KK + kc);
        float4 ya = *(const float4*)(ys + y0 * 256 + ((g ^ ysw0) << 2));
        float4 yb = *(const float4*)(ys + y1 * 256 + ((g ^ ysw1) << 2));
        float4 za = *(const float4*)(zs + z0 * 256 + ((g ^ zsw0) << 2));
        float4 zb = *(const float4*)(zs + z1 * 256 + ((g ^ zsw1) << 2));
#define TAN_STEP(c) { \
        float xs = sh * xv.c; \
        float w0 = xs * vh0.c, w1 = xs * vh1.c; \
        float t00 = w0 * ya.c, t01 = w0 * yb.c; \
        float t10 = w1 * ya.c, t11 = w1 * yb.c; \
        a000 = fmaf(t00, za.c, a000); a001 = fmaf(t00, zb.c, a001); \
        a010 = fmaf(t01, za.c, a010); a011 = fmaf(t01, zb.c, a011); \
        a100 = fmaf(t10, za.c, a100); a101 = fmaf(t10, zb.c, a101); \
        a110 = fmaf(t11, za.c, a110); a111 = fmaf(t11, zb.c, a111); }
        TAN_STEP(x) TAN_STEP(y) TAN_STEP(z) TAN_STEP(w)
#undef TAN_STEP
    }

    float b0 = bh[0], b1 = bh[1];
    a000 += b0; a001 += b0; a010 += b0; a011 += b0;
    a100 += b1; a101 += b1; a110 += b1; a111 += b1;
    float* r0 = ws + WS_RAW + (bb * 2 + 0) * XYZ + xx * 1024;
    float* r1 = r0 + XYZ;
    r0[y0 * 32 + z0] = a000;  r0[y0 * 32 + z1] = a001;
    r0[y1 * 32 + z0] = a010;  r0[y1 * 32 + z1] = a011;
    r1[y0 * 32 + z0] = a100;  r1[y0 * 32 + z1] = a101;
    r1[y1 * 32 + z0] = a110;  r1[y1 * 32 + z1] = a111;

    // per-(b,x) online softmax partials
    float m0 = fmaxf(fmaxf(a000, a001), fmaxf(a010, a011));
    float l0 = __expf(a000 - m0) + __expf(a001 - m0)
             + __expf(a010 - m0) + __expf(a011 - m0);
    float m1 = fmaxf(fmaxf(a100, a101), fmaxf(a110, a111));
    float l1 = __expf(a100 - m1) + __expf(a101 - m1)
             + __expf(a110 - m1) + __expf(a111 - m1);
#pragma unroll
    for (int o = 1; o < 64; o <<= 1) {
        float mo = __shfl_xor(m0, o), lo = __shfl_xor(l0, o);
        float nm = fmaxf(m0, mo);
        l0 = l0 * __expf(m0 - nm) + lo * __expf(mo - nm); m0 = nm;
        mo = __shfl_xor(m1, o); lo = __shfl_xor(l1, o);
        nm = fmaxf(m1, mo);
        l1 = l1 * __expf(m1 - nm) + lo * __expf(mo - nm); m1 = nm;
    }
    if ((t & 63) == 0) {
        int w = t >> 6;
        smred[w][0] = m0; smred[w][1] = l0;
        smred[w][2] = m1; smred[w][3] = l1;
    }
    __syncthreads();
    if (t == 0) {
        float M0 = smred[0][0], L0 = smred[0][1];
        float M1 = smred[0][2], L1 = smred[0][3];
#pragma unroll
        for (int w = 1; w < 4; ++w) {
            float nm = fmaxf(M0, smred[w][0]);
            L0 = L0 * __expf(M0 - nm) + smred[w][1] * __expf(smred[w][0] - nm);
            M0 = nm;
            nm = fmaxf(M1, smred[w][2]);
            L1 = L1 * __expf(M1 - nm) + smred[w][3] * __expf(smred[w][2] - nm);
            M1 = nm;
        }
        float* sm = ws + WS_SM + (bb * 32 + xx) * 4;
        sm[0] = M0; sm[1] = L0; sm[2] = M1; sm[3] = L1;
    }
}

// ---------------------------------------------------------------- fused softmax-finalize + logits
// grid 256: b = bid>>5, x = bid&31; 256 threads (thread = k).
__global__ void __launch_bounds__(256)
tan_logits_kernel(float* ws, float* out) {
    __shared__ float as4[1024];
    __shared__ float cons[4];
    int b = blockIdx.x >> 5;
    int x = blockIdx.x & 31;
    int t = threadIdx.x;
    const float* _zb = ws + WS_Z + b * 8192;
    float zreg[32];
#pragma unroll
    for (int zi = 0; zi < 32; ++zi) zreg[zi] = _zb[zi * 256 + t];

    if (t < 64) {
        const float* sm = ws + WS_SM + (b * 32 + (t & 31)) * 4;
        float4 p = *(const float4*)sm;
        float m0 = p.x, l0 = p.y, m1 = p.z, l1 = p.w;
#pragma unroll
        for (int o = 1; o < 32; o <<= 1) {
            float mo = __shfl_xor(m0, o), lo = __shfl_xor(l0, o);
            float nm = fmaxf(m0, mo);
            l0 = l0 * __expf(m0 - nm) + lo * __expf(mo - nm); m0 = nm;
            mo = __shfl_xor(m1, o); lo = __shfl_xor(l1, o);
            nm = fmaxf(m1, mo);
            l1 = l1 * __expf(m1 - nm) + lo * __expf(mo - nm); m1 = nm;
        }
        if (t == 0) {
            cons[0] = m0; cons[1] = 1.f / l0;
            cons[2] = m1; cons[3] = 1.f / l1;
        }
    }
    __syncthreads();
    float M0 = cons[0], inv0 = cons[1], M1 = cons[2], inv1 = cons[3];
    const float* r0 = ws + WS_RAW + (b * 2) * XYZ + x * 1024;
    const float* r1 = r0 + XYZ;
    float* o0 = out + BB * KK + (b * 2) * XYZ + x * 1024;
    float* o1 = o0 + XYZ;
#pragma unroll
    for (int i = t; i < 1024; i += 256) {
        float a0 = __expf(r0[i] - M0) * inv0;
        float a1 = __expf(r1[i] - M1) * inv1;
        o0[i] = a0; o1[i] = a1;
        as4[i] = a0 + a1;
    }
    __syncthreads();

    const float* _yb = ws + WS_Y + b * 8192;
    float acc = 0.f;
#pragma unroll 4
    for (int y = 0; y < 32; ++y) {
        float s = 0.f;
        const float4* ar = (const float4*)(as4 + y * 32);
#pragma unroll
        for (int j = 0; j < 8; ++j) {
            float4 a = ar[j];
            s += a.x * zreg[j * 4] + a.y * zreg[j * 4 + 1]
               + a.z * zreg[j * 4 + 2] + a.w * zreg[j * 4 + 3];
        }
        acc = fmaf(_yb[y * 256 + t], s, acc);
    }
    float xv = ws[WS_X + (b * 32 + x) * 256 + t];
    atomicAdd(ws + WS_LOG + b * 256 + t, xv * acc);
}

// ---------------------------------------------------------------- batchnorm
// 1 block, 256 threads (thread = k); reads the 8KB logits accumulator.
__global__ void __launch_bounds__(256)
tan_bn_kernel(const float* ws, const float* gamma, const float* beta, float* out) {
    int k = threadIdx.x;
    const float* lgp = ws + WS_LOG;
    float lg[BB];
#pragma unroll
    for (int b = 0; b < BB; ++b) lg[b] = lgp[b * 256 + k];
    float mean = 0.f;
#pragma unroll
    for (int b = 0; b < BB; ++b) mean += lg[b];
    mean *= 0.125f;
    float var = 0.f;
#pragma unroll
    for (int b = 0; b < BB; ++b) { float d = lg[b] - mean; var += d * d; }
    var *= 0.125f;
    float inv = rsqrtf(var + EPSV);
    float gm = gamma[k], bt = beta[k];
#pragma unroll
    for (int b = 0; b < BB; ++b)
        out[b * 256 + k] = (lg[b] - mean) * inv * gm + bt;
}

extern "C" void kernel_launch(void* const* d_in, const int* in_sizes, int n_in,
                              void* d_out, int out_size, void* d_ws, size_t ws_size,
                              hipStream_t stream) {
    (void)in_sizes; (void)n_in; (void)out_size; (void)ws_size;
    const float* x     = (const float*)d_in[0];
    const float* y     = (const float*)d_in[1];
    const float* z     = (const float*)d_in[2];
    const float* Vx    = (const float*)d_in[3];
    const float* gx    = (const float*)d_in[4];
    const float* bx    = (const float*)d_in[5];
    const float* Vy    = (const float*)d_in[6];
    const float* gy    = (const float*)d_in[7];
    const float* by    = (const float*)d_in[8];
    const float* Vz    = (const float*)d_in[9];
    const float* gz    = (const float*)d_in[10];
    const float* bz    = (const float*)d_in[11];
    const float* Vh    = (const float*)d_in[12];
    const float* gh    = (const float*)d_in[13];
    const float* bh    = (const float*)d_in[14];
    const float* gamma = (const float*)d_in[15];
    const float* beta  = (const float*)d_in[16];
    float* ws  = (float*)d_ws;
    float* out = (float*)d_out;

    hipMemsetAsync(ws + WS_LOG, 0, 2048 * sizeof(float), stream);
    tan_proj_kernel<<<192, 256, 0, stream>>>(x, y, z, Vx, Vy, Vz,
                                             gx, gy, gz, bx, by, bz, ws);
    tan_score_kernel<<<256, 256, 0, stream>>>(Vh, gh, bh, ws);
    tan_logits_kernel<<<256, 256, 0, stream>>>(ws, out);
    tan_bn_kernel<<<1, 256, 0, stream>>>(ws, gamma, beta, out);
}